// Round 8
// baseline (415.968 us; speedup 1.0000x reference)
//
#include <hip/hip_runtime.h>
#include <hip/hip_bf16.h>

typedef unsigned int uint;
typedef unsigned short ushort;
typedef __attribute__((ext_vector_type(8))) short bf16x8;
typedef __attribute__((ext_vector_type(4))) float f32x4;
typedef __attribute__((ext_vector_type(16))) float f32x16;

__device__ __forceinline__ float bf2f(ushort u) {
    return __uint_as_float(((uint)u) << 16);
}
__device__ __forceinline__ ushort f2bf(float f) {
    uint u = __float_as_uint(f);
    u += 0x7FFFu + ((u >> 16) & 1u);   // round-to-nearest-even
    return (ushort)(u >> 16);
}
__device__ __forceinline__ uint cvtpk(float lo, float hi) {
    uint r;
    asm("v_cvt_pk_bf16_f32 %0, %1, %2" : "=v"(r) : "v"(lo), "v"(hi));
    return r;
}
__device__ __forceinline__ float sigm(float x) {
    return 1.0f / (1.0f + expf(-x));
}
// async global->LDS DMA, 16 B per lane; lds dest = wave-uniform base + lane*16
__device__ __forceinline__ void dma16(const void* g, void* l) {
    __builtin_amdgcn_global_load_lds(
        (const __attribute__((address_space(1))) void*)g,
        (__attribute__((address_space(3))) void*)l, 16, 0, 0);
}

// ---------------- kernel 1: fused kP (blocks 0-95) + kW (blocks 96-119)
__global__ __launch_bounds__(512) void kPW(
    const float* __restrict__ emb, const float* __restrict__ w_ih,
    const float* __restrict__ b_ih, float* __restrict__ P,
    const float* __restrict__ g_w2, const float* __restrict__ g_w3,
    const float* __restrict__ g_w4, ushort* __restrict__ Wst)
{
    int tid = threadIdx.x;
    if (blockIdx.x < 96) {
        __shared__ __align__(16) float te[300];
        int v = blockIdx.x;
        for (int k = tid; k < 300; k += 512) te[k] = tanhf(emb[v * 300 + k]);
        __syncthreads();
        int g = tid;
        float acc = b_ih[g];
        const float4* wr = (const float4*)(w_ih + g * 300);
        const float4* tv = (const float4*)te;
        for (int k = 0; k < 75; ++k) {
            float4 w4 = wr[k], t4 = tv[k];
            acc += w4.x * t4.x + w4.y * t4.y + w4.z * t4.z + w4.w * t4.w;
        }
        P[v * 512 + g] = acc;
    } else if (tid < 256) {
        // Wst chunks [li][kc][col][slot], bank-swizzle baked into global layout
        int blk = blockIdx.x - 96;
        int li = blk >> 3, kc = blk & 7, col = tid;
        const float* W = (li == 0) ? g_w2 : (li == 1) ? g_w3 : g_w4;
        ushort* dst = Wst + li * 65536 + kc * 8192;
        for (int kk = 0; kk < 32; ++kk) {
            int slot = (kk >> 3) ^ ((col >> 1) & 3);
            dst[col * 32 + slot * 8 + (kk & 7)] = f2bf(W[(kc * 32 + kk) * 256 + col]);
        }
    }
}

// ---------------- kernel 2: fused LSTM (w_hh LDS-resident bf16) -> Wq -> A1/A2
__global__ __launch_bounds__(256) void kLA(
    const float* __restrict__ P, const float* __restrict__ w_hh,
    const float* __restrict__ b_hh, const float* __restrict__ g_w1,
    const float* __restrict__ g_b1, const int* __restrict__ q_feats,
    const int* __restrict__ q_lens, const float* __restrict__ box_feats,
    ushort* __restrict__ A1, ushort* __restrict__ A2)
{
    __shared__ __align__(16) ushort whh[512 * 128];   // 128 KB, slot-XOR swizzled
    __shared__ __align__(16) float h[128];
    __shared__ __align__(16) float c[128];
    __shared__ float gates[512];
    __shared__ float wq[256];
    __shared__ float box[64][26];
    int b = blockIdx.x, tid = threadIdx.x;          // block 256
    if (tid < 128) { h[tid] = 0.f; c[tid] = 0.f; }
    // stage w_hh -> LDS bf16; block k8 stored at slot k8^(g&7)
    for (int i = tid * 4; i < 65536; i += 1024) {
        int g = i >> 7, k = i & 127, k8 = k >> 3;
        float4 w4 = *(const float4*)&w_hh[i];
        uint2 o;
        o.x = cvtpk(w4.x, w4.y);
        o.y = cvtpk(w4.z, w4.w);
        *(uint2*)&whh[g * 128 + ((k8 ^ (g & 7)) << 3) + (k & 7)] = o;
    }
    for (int idx = tid; idx < 64 * 26; idx += 256) {
        int n = idx / 26, d = idx - n * 26;
        float v;
        if (d < 24)       v = box_feats[(b * 64 + n) * 24 + d];
        else if (d == 24) v = ((n >> 3) - 4) * 0.125f;
        else              v = ((n & 7) - 4) * 0.125f;
        box[n][d] = v;
    }
    __syncthreads();
    int len = q_lens[b];                             // c,h frozen after len
    const int sx = (tid & 7);
    for (int t = 0; t < len; ++t) {
        int idx = q_feats[b * 20 + t];
        #pragma unroll
        for (int gp = 0; gp < 2; ++gp) {
            int g = tid + gp * 256;                  // g&7 == sx
            float acc = P[idx * 512 + g] + b_hh[g];
            const ushort* wr = &whh[g * 128];
            #pragma unroll
            for (int k8 = 0; k8 < 16; ++k8) {
                // slot (k8^sx) of row g holds k-block (k8^sx)^(g&7) == k8
                bf16x8 w8 = *(const bf16x8*)&wr[(k8 ^ sx) << 3];
                const float* hv = &h[k8 * 8];
                #pragma unroll
                for (int j = 0; j < 8; ++j)
                    acc += bf2f((ushort)w8[j]) * hv[j];
            }
            gates[g] = acc;
        }
        __syncthreads();
        if (tid < 128) {
            float ig = sigm(gates[tid]);
            float fg = sigm(gates[128 + tid]);
            float gg = tanhf(gates[256 + tid]);
            float og = sigm(gates[384 + tid]);
            float cn = fg * c[tid] + ig * gg;
            c[tid] = cn;
            h[tid] = og * tanhf(cn);
        }
        __syncthreads();
    }
    {
        float acc = g_b1[tid];
        for (int k = 0; k < 128; ++k) acc += c[k] * g_w1[(52 + k) * 256 + tid];
        wq[tid] = acc;
    }
    __syncthreads();
    float w1a[26], w1b[26];
    #pragma unroll
    for (int d = 0; d < 26; ++d) {
        w1a[d] = g_w1[d * 256 + tid];
        w1b[d] = g_w1[(26 + d) * 256 + tid];
    }
    float wqv = wq[tid];
    for (int n = 0; n < 64; ++n) {
        float a1 = 0.f, a2 = wqv;
        #pragma unroll
        for (int d = 0; d < 26; ++d) {
            a1 += box[n][d] * w1a[d];
            a2 += box[n][d] * w1b[d];
        }
        A1[(b * 64 + n) * 256 + tid] = f2bf(a1);
        A2[(b * 64 + n) * 256 + tid] = f2bf(a2);
    }
}

// ---------------- kernel 3: pair-MLP, 1024 threads, 32x32x16 MFMA, 4 waves/SIMD
#define MFMA32(wa, xb, a) __builtin_amdgcn_mfma_f32_32x32x16_bf16(wa, xb, a, 0, 0, 0)

// one 16 KB W chunk: 16 waves x 1 KB DMA each
#define DMA_CHUNK(Q, BUF)                                                       \
    do {                                                                        \
        const char* gs_ = (const char*)Wst + (Q) * 16384 + wv * 1024 + (lane << 4); \
        char* ls_ = ((char*)lds_w[BUF]) + wv * 1024;                            \
        dma16(gs_, ls_);                                                        \
    } while (0)

__global__ __launch_bounds__(1024) void kD(
    const ushort* __restrict__ A1, const ushort* __restrict__ A2,
    const ushort* __restrict__ Wst,
    const float* __restrict__ b2, const float* __restrict__ b3,
    const float* __restrict__ b4, float* __restrict__ partial)
{
    __shared__ __align__(16) ushort lds_x[256 * 256];   // 131072 B, XOR-swizzled rows
    __shared__ __align__(16) ushort lds_w[2][8192];     // 2 x 16384 B (DMA dbuf)

    const int tid = threadIdx.x;
    const int b = blockIdx.x >> 4, iblk = blockIdx.x & 15;   // 4 pairs: i = iblk*4+p
    const int lane = tid & 63, wv = tid >> 6;                // 16 waves
    const int l31 = lane & 31, e8 = lane >> 5;
    const int rg = wv & 3, cg = wv >> 2;
    const int wrow0 = rg * 64, col0 = cg * 64;               // wave tile 64r x 64c

    // chunk-0 DMA first: lands in buf0 while we build X
    DMA_CHUNK(0, 0);

    // ---- a1 rows in registers (transient; dead after build)
    const int l0 = (tid & 31) << 3;
    bf16x8 a1r[4];
    #pragma unroll
    for (int p = 0; p < 4; ++p)
        a1r[p] = *(const bf16x8*)&A1[(b * 64 + iblk * 4 + p) * 256 + l0];

    // ---- build X1 (swizzled): X[p*64+j][l] = relu(a1[p][l] + A2[b,j][l])
    const ushort* A2b = A2 + b * 64 * 256;
    #pragma unroll
    for (int p8 = 0; p8 < 8; ++p8) {
        int row = p8 * 32 + (tid >> 5);        // 0..255, each exactly once
        int j = row & 63, p = row >> 6;
        uint4 v = *(const uint4*)(A2b + j * 256 + l0);
        uint vv[4] = {v.x, v.y, v.z, v.w}, ov[4];
        #pragma unroll
        for (int qq = 0; qq < 4; ++qq) {
            float f0 = bf2f((ushort)a1r[p][2 * qq])     + bf2f((ushort)(vv[qq] & 0xFFFFu));
            float f1 = bf2f((ushort)a1r[p][2 * qq + 1]) + bf2f((ushort)(vv[qq] >> 16));
            ov[qq] = cvtpk(fmaxf(f0, 0.f), fmaxf(f1, 0.f));
        }
        *(uint4*)&lds_x[row * 256 + (l0 ^ ((row & 7) << 3))] =
            make_uint4(ov[0], ov[1], ov[2], ov[3]);
    }
    __syncthreads();   // drains vmcnt+lgkm: chunk0 resident in buf0, X ready

    int q = 0;   // linear chunk index li*8+kc
    #pragma unroll 1
    for (int li = 0; li < 3; ++li) {
        f32x16 acc[2][2];
        #pragma unroll
        for (int rt = 0; rt < 2; ++rt)
            #pragma unroll
            for (int ct = 0; ct < 2; ++ct)
                #pragma unroll
                for (int r = 0; r < 16; ++r)
                    acc[rt][ct][r] = 0.f;

        #pragma unroll 1
        for (int kc = 0; kc < 8; ++kc, ++q) {
            if (q < 23) DMA_CHUNK(q + 1, (q + 1) & 1);
            const ushort* wb = lds_w[q & 1];
            #pragma unroll
            for (int ks = 0; ks < 2; ++ks) {
                int colA0 = col0 + l31, colA1 = col0 + 32 + l31;
                bf16x8 wa0 = *(const bf16x8*)
                    &wb[colA0 * 32 + (((ks * 2 + e8) ^ ((colA0 >> 1) & 3)) << 3)];
                bf16x8 wa1 = *(const bf16x8*)
                    &wb[colA1 * 32 + (((ks * 2 + e8) ^ ((colA1 >> 1) & 3)) << 3)];
                int rowB0 = wrow0 + l31, rowB1 = wrow0 + 32 + l31;
                int kkcol = kc * 32 + ks * 16 + e8 * 8;
                bf16x8 xb0 = *(const bf16x8*)
                    &lds_x[rowB0 * 256 + (kkcol ^ ((rowB0 & 7) << 3))];
                bf16x8 xb1 = *(const bf16x8*)
                    &lds_x[rowB1 * 256 + (kkcol ^ ((rowB1 & 7) << 3))];
                __builtin_amdgcn_s_setprio(1);
                acc[0][0] = MFMA32(wa0, xb0, acc[0][0]);
                acc[0][1] = MFMA32(wa1, xb0, acc[0][1]);
                acc[1][0] = MFMA32(wa0, xb1, acc[1][0]);
                acc[1][1] = MFMA32(wa1, xb1, acc[1][1]);
                __builtin_amdgcn_s_setprio(0);
            }
            asm volatile("s_waitcnt vmcnt(0) lgkmcnt(0)" ::: "memory");
            __builtin_amdgcn_sched_barrier(0);
            __builtin_amdgcn_s_barrier();
        }

        const float* bias = (li == 0) ? b2 : (li == 1) ? b3 : b4;
        // D layout 32x32: X-row = lane&31 (+rt*32+wrow0); W-col = dcol(reg,e8)
        //   dcol = (reg&3) + 8*(reg>>2) + 4*e8  -> 4 runs of 4: r*8 + 4*e8 + 0..3
        if (li < 2) {
            // all lds_x reads retired before last chunk's barrier; overwrite in place
            #pragma unroll
            for (int rt = 0; rt < 2; ++rt) {
                int row = wrow0 + rt * 32 + l31;
                int sw = (row & 7) << 3;
                #pragma unroll
                for (int ct = 0; ct < 2; ++ct) {
                    f32x16 a = acc[rt][ct];
                    #pragma unroll
                    for (int r = 0; r < 4; ++r) {
                        int cb = col0 + ct * 32 + r * 8 + 4 * e8;
                        f32x4 bv = *(const f32x4*)(bias + cb);
                        uint2 pk;
                        pk.x = cvtpk(fmaxf(a[4 * r + 0] + bv[0], 0.f),
                                     fmaxf(a[4 * r + 1] + bv[1], 0.f));
                        pk.y = cvtpk(fmaxf(a[4 * r + 2] + bv[2], 0.f),
                                     fmaxf(a[4 * r + 3] + bv[3], 0.f));
                        *(uint2*)&lds_x[row * 256 + (cb ^ sw)] = pk;
                    }
                }
            }
            asm volatile("s_waitcnt lgkmcnt(0)" ::: "memory");
            __builtin_amdgcn_sched_barrier(0);
            __builtin_amdgcn_s_barrier();
        } else {
            // ---- final layer: reduce over this wave's 64 X-rows (pair p = rg)
            #pragma unroll
            for (int ct = 0; ct < 2; ++ct) {
                float s[16];
                #pragma unroll
                for (int r = 0; r < 4; ++r) {
                    int cb = col0 + ct * 32 + r * 8 + 4 * e8;
                    f32x4 bv = *(const f32x4*)(bias + cb);
                    #pragma unroll
                    for (int e = 0; e < 4; ++e)
                        s[4 * r + e] = fmaxf(acc[0][ct][4 * r + e] + bv[e], 0.f)
                                     + fmaxf(acc[1][ct][4 * r + e] + bv[e], 0.f);
                }
                // reduce over lane&31 (X-rows); masks 1..16 stay within 32-halves
                #pragma unroll
                for (int m = 1; m < 32; m <<= 1)
                    #pragma unroll
                    for (int r = 0; r < 16; ++r)
                        s[r] += __shfl_xor(s[r], m, 64);
                if (l31 == 0) {
                    int prow = b * 64 + iblk * 4 + rg;
                    #pragma unroll
                    for (int r = 0; r < 4; ++r) {
                        float4 o = {s[4 * r + 0], s[4 * r + 1],
                                    s[4 * r + 2], s[4 * r + 3]};
                        *(float4*)&partial[prow * 256 + col0 + ct * 32
                                           + r * 8 + 4 * e8] = o;
                    }
                }
            }
        }
    }
}

// ---------------- kernel 4: fused reduce + f-network, one block per b
__global__ __launch_bounds__(256) void kRF(
    const float* __restrict__ partial,
    const float* __restrict__ f_w1, const float* __restrict__ f_b1,
    const float* __restrict__ f_w2, const float* __restrict__ f_b2,
    const float* __restrict__ f_w3, const float* __restrict__ f_b3,
    float* __restrict__ out)
{
    __shared__ float g[256], y1[256], y2[256];
    int b = blockIdx.x, t = threadIdx.x;       // block 256
    {
        float s = 0.f;
        const float* pb = partial + b * 64 * 256 + t;
        #pragma unroll 8
        for (int i = 0; i < 64; ++i) s += pb[i * 256];
        g[t] = s;
    }
    __syncthreads();
    float acc = f_b1[t];
    for (int k = 0; k < 256; ++k) acc += g[k] * f_w1[k * 256 + t];
    y1[t] = fmaxf(acc, 0.f);
    __syncthreads();
    acc = f_b2[t];
    for (int k = 0; k < 256; ++k) acc += y1[k] * f_w2[k * 256 + t];
    y2[t] = fmaxf(acc, 0.f);
    __syncthreads();
    if (t < 100) {
        float o = f_b3[t];
        for (int k = 0; k < 256; ++k) o += y2[k] * f_w3[k * 100 + t];
        out[b * 100 + t] = o;
    }
}

extern "C" void kernel_launch(void* const* d_in, const int* in_sizes, int n_in,
                              void* d_out, int out_size, void* d_ws, size_t ws_size,
                              hipStream_t stream)
{
    const float* box_feats = (const float*)d_in[0];
    const float* emb   = (const float*)d_in[1];
    const float* w_ih  = (const float*)d_in[2];
    const float* w_hh  = (const float*)d_in[3];
    const float* b_ih  = (const float*)d_in[4];
    const float* b_hh  = (const float*)d_in[5];
    const float* g_w1  = (const float*)d_in[6];
    const float* g_b1  = (const float*)d_in[7];
    const float* g_w2  = (const float*)d_in[8];
    const float* g_b2  = (const float*)d_in[9];
    const float* g_w3  = (const float*)d_in[10];
    const float* g_b3  = (const float*)d_in[11];
    const float* g_w4  = (const float*)d_in[12];
    const float* g_b4  = (const float*)d_in[13];
    const float* f_w1  = (const float*)d_in[14];
    const float* f_b1  = (const float*)d_in[15];
    const float* f_w2  = (const float*)d_in[16];
    const float* f_b2  = (const float*)d_in[17];
    const float* f_w3  = (const float*)d_in[18];
    const float* f_b3  = (const float*)d_in[19];
    const int* q_feats = (const int*)d_in[20];
    const int* q_lens  = (const int*)d_in[21];
    float* out = (float*)d_out;

    char* ws = (char*)d_ws;
    float*  P    = (float*) (ws + 0);          //  96*512*4   = 196608
    ushort* A1   = (ushort*)(ws + 196608);     // 8192*256*2  = 4194304
    ushort* A2   = (ushort*)(ws + 4390912);    // 8192*256*2  = 4194304
    ushort* Wst  = (ushort*)(ws + 8585216);    // 3*65536*2   = 393216
    float*  part = (float*) (ws + 8978432);    // 8192*256*4  = 8388608

    hipLaunchKernelGGL(kPW, dim3(120),  dim3(512), 0, stream,
                       emb, w_ih, b_ih, P, g_w2, g_w3, g_w4, Wst);
    hipLaunchKernelGGL(kLA, dim3(128),  dim3(256), 0, stream,
                       P, w_hh, b_hh, g_w1, g_b1, q_feats, q_lens, box_feats, A1, A2);
    hipLaunchKernelGGL(kD,  dim3(2048), dim3(1024), 0, stream,
                       A1, A2, Wst, g_b2, g_b3, g_b4, part);
    hipLaunchKernelGGL(kRF, dim3(128),  dim3(256), 0, stream,
                       part, f_w1, f_b1, f_w2, f_b2, f_w3, f_b3, out);
}

// Round 9
// 366.961 us; speedup vs baseline: 1.1335x; 1.1335x over previous
//
#include <hip/hip_runtime.h>
#include <hip/hip_bf16.h>

typedef unsigned int uint;
typedef unsigned short ushort;
typedef __attribute__((ext_vector_type(8))) short bf16x8;
typedef __attribute__((ext_vector_type(4))) float f32x4;

__device__ __forceinline__ float bf2f(ushort u) {
    return __uint_as_float(((uint)u) << 16);
}
__device__ __forceinline__ ushort f2bf(float f) {
    uint u = __float_as_uint(f);
    u += 0x7FFFu + ((u >> 16) & 1u);   // round-to-nearest-even
    return (ushort)(u >> 16);
}
__device__ __forceinline__ uint cvtpk(float lo, float hi) {
    uint r;
    asm("v_cvt_pk_bf16_f32 %0, %1, %2" : "=v"(r) : "v"(lo), "v"(hi));
    return r;
}
__device__ __forceinline__ float sigm(float x) {
    return 1.0f / (1.0f + expf(-x));
}
// async global->LDS DMA, 16 B per lane; lds dest = wave-uniform base + lane*16
__device__ __forceinline__ void dma16(const void* g, void* l) {
    __builtin_amdgcn_global_load_lds(
        (const __attribute__((address_space(1))) void*)g,
        (__attribute__((address_space(3))) void*)l, 16, 0, 0);
}

// ---------------- kernel 1: fused kP (blocks 0-95) + kW (blocks 96-119)
__global__ __launch_bounds__(512) void kPW(
    const float* __restrict__ emb, const float* __restrict__ w_ih,
    const float* __restrict__ b_ih, float* __restrict__ P,
    const float* __restrict__ g_w2, const float* __restrict__ g_w3,
    const float* __restrict__ g_w4, ushort* __restrict__ Wst)
{
    int tid = threadIdx.x;
    if (blockIdx.x < 96) {
        __shared__ __align__(16) float te[300];
        int v = blockIdx.x;
        for (int k = tid; k < 300; k += 512) te[k] = tanhf(emb[v * 300 + k]);
        __syncthreads();
        int g = tid;
        float acc = b_ih[g];
        const float4* wr = (const float4*)(w_ih + g * 300);
        const float4* tv = (const float4*)te;
        for (int k = 0; k < 75; ++k) {
            float4 w4 = wr[k], t4 = tv[k];
            acc += w4.x * t4.x + w4.y * t4.y + w4.z * t4.z + w4.w * t4.w;
        }
        P[v * 512 + g] = acc;
    } else if (tid < 256) {
        // Wst chunks [li][kc][col][slot], bank-swizzle baked into global layout
        int blk = blockIdx.x - 96;
        int li = blk >> 3, kc = blk & 7, col = tid;
        const float* W = (li == 0) ? g_w2 : (li == 1) ? g_w3 : g_w4;
        ushort* dst = Wst + li * 65536 + kc * 8192;
        for (int kk = 0; kk < 32; ++kk) {
            int slot = (kk >> 3) ^ ((col >> 1) & 3);
            dst[col * 32 + slot * 8 + (kk & 7)] = f2bf(W[(kc * 32 + kk) * 256 + col]);
        }
    }
}

// ---------------- kernel 2: fused LSTM -> Wq -> A1/A2, 512 threads, 1 gate/thread
#define WROW 132   // padded w_hh row (ushort): 264 B -> 2-way banks on b64 reads
__global__ __launch_bounds__(512) void kLA(
    const float* __restrict__ P, const float* __restrict__ w_hh,
    const float* __restrict__ b_hh, const float* __restrict__ g_w1,
    const float* __restrict__ g_b1, const int* __restrict__ q_feats,
    const int* __restrict__ q_lens, const float* __restrict__ box_feats,
    ushort* __restrict__ A1, ushort* __restrict__ A2)
{
    __shared__ __align__(16) ushort whh[512 * WROW];   // 135168 B
    __shared__ __align__(16) float h[128];
    __shared__ __align__(16) float c[128];
    __shared__ float gates[512];
    __shared__ float wq2[2][256];
    __shared__ float box[64][26];
    int b = blockIdx.x, tid = threadIdx.x;          // block 512
    if (tid < 128) { h[tid] = 0.f; c[tid] = 0.f; }
    // stage w_hh -> LDS bf16, padded rows (no swizzle needed at stride 264B)
    for (int i = tid * 4; i < 65536; i += 2048) {
        int g = i >> 7, k = i & 127;
        float4 w4 = *(const float4*)&w_hh[i];
        uint2 o;
        o.x = cvtpk(w4.x, w4.y);
        o.y = cvtpk(w4.z, w4.w);
        *(uint2*)&whh[g * WROW + k] = o;
    }
    for (int idx = tid; idx < 64 * 26; idx += 512) {
        int n = idx / 26, d = idx - n * 26;
        float v;
        if (d < 24)       v = box_feats[(b * 64 + n) * 24 + d];
        else if (d == 24) v = ((n >> 3) - 4) * 0.125f;
        else              v = ((n & 7) - 4) * 0.125f;
        box[n][d] = v;
    }
    __syncthreads();
    int len = q_lens[b];                             // c,h frozen after len
    const int g = tid;
    const ushort* wr = &whh[g * WROW];
    for (int t = 0; t < len; ++t) {
        int idx = q_feats[b * 20 + t];
        float acc = P[idx * 512 + g] + b_hh[g];
        #pragma unroll
        for (int k8 = 0; k8 < 16; ++k8) {
            uint2 wlo = *(const uint2*)&wr[k8 * 8];
            uint2 whi = *(const uint2*)&wr[k8 * 8 + 4];
            float4 h0 = *(const float4*)&h[k8 * 8];
            float4 h1 = *(const float4*)&h[k8 * 8 + 4];
            acc += bf2f((ushort)(wlo.x & 0xFFFFu)) * h0.x
                 + bf2f((ushort)(wlo.x >> 16))     * h0.y
                 + bf2f((ushort)(wlo.y & 0xFFFFu)) * h0.z
                 + bf2f((ushort)(wlo.y >> 16))     * h0.w
                 + bf2f((ushort)(whi.x & 0xFFFFu)) * h1.x
                 + bf2f((ushort)(whi.x >> 16))     * h1.y
                 + bf2f((ushort)(whi.y & 0xFFFFu)) * h1.z
                 + bf2f((ushort)(whi.y >> 16))     * h1.w;
        }
        gates[g] = acc;
        __syncthreads();
        if (tid < 128) {
            float ig = sigm(gates[tid]);
            float fg = sigm(gates[128 + tid]);
            float gg = tanhf(gates[256 + tid]);
            float og = sigm(gates[384 + tid]);
            float cn = fg * c[tid] + ig * gg;
            c[tid] = cn;
            h[tid] = og * tanhf(cn);
        }
        __syncthreads();
    }
    // Wq split across 2 half-sums
    {
        int l = tid & 255, half = tid >> 8;
        float acc = (half == 0) ? g_b1[l] : 0.f;
        for (int k = 0; k < 64; ++k)
            acc += c[half * 64 + k] * g_w1[(52 + half * 64 + k) * 256 + l];
        wq2[half][l] = acc;
    }
    __syncthreads();
    {
        int l = tid & 255, n0 = tid >> 8;
        float w1a[26], w1b[26];
        #pragma unroll
        for (int d = 0; d < 26; ++d) {
            w1a[d] = g_w1[d * 256 + l];
            w1b[d] = g_w1[(26 + d) * 256 + l];
        }
        float wqv = wq2[0][l] + wq2[1][l];
        for (int n = n0; n < 64; n += 2) {
            float a1 = 0.f, a2 = wqv;
            #pragma unroll
            for (int d = 0; d < 26; ++d) {
                a1 += box[n][d] * w1a[d];
                a2 += box[n][d] * w1b[d];
            }
            A1[(b * 64 + n) * 256 + l] = f2bf(a1);
            A2[(b * 64 + n) * 256 + l] = f2bf(a2);
        }
    }
}

// ---------------- kernel 3: pair-MLP, 1 pair/block, 64KB LDS -> 2 blocks/CU
#define MFMA1(wa, xb, a) __builtin_amdgcn_mfma_f32_16x16x32_bf16(wa, xb, a, 0, 0, 0)

#define DMA_CHUNK(Q, BUF)                                                       \
    do {                                                                        \
        const char* gs_ = (const char*)Wst + (Q) * 16384 + wv * 1024 + (lane << 4); \
        char* ls_ = ((char*)lds_w[BUF]) + wv * 1024;                            \
        dma16(gs_, ls_);                                                        \
        dma16(gs_ + 8192, ls_ + 8192);                                          \
    } while (0)

__global__ __launch_bounds__(512, 4) void kD(
    const ushort* __restrict__ A1, const ushort* __restrict__ A2,
    const ushort* __restrict__ Wst,
    const float* __restrict__ b2, const float* __restrict__ b3,
    const float* __restrict__ b4, float* __restrict__ partial)
{
    __shared__ __align__(16) ushort lds_x[64 * 256];    // 32768 B, XOR-swizzled rows
    __shared__ __align__(16) ushort lds_w[2][8192];     // 2 x 16384 B (DMA dbuf)

    const int tid = threadIdx.x;
    const int bi = blockIdx.x, b = bi >> 6;             // one (b,i) pair per block
    const int lane = tid & 63, wv = tid >> 6;           // 8 waves
    const int l15 = lane & 15, lg = lane >> 4;
    const int col0 = wv * 32;                           // wave tile 64r x 32c

    // chunk-0 DMA first: lands in buf0 while we build X
    DMA_CHUNK(0, 0);

    // ---- build X1 (swizzled): X[j][l] = relu(A1[bi][l] + A2[b,j][l])
    const ushort* A1r = A1 + bi * 256;
    const ushort* A2b = A2 + b * 64 * 256;
    #pragma unroll
    for (int it = 0; it < 4; ++it) {
        int task = it * 512 + tid;
        int row = task >> 5, l0 = (task & 31) << 3;
        uint4 v = *(const uint4*)(A2b + row * 256 + l0);
        bf16x8 a1v = *(const bf16x8*)(A1r + l0);
        uint vv[4] = {v.x, v.y, v.z, v.w}, ov[4];
        #pragma unroll
        for (int qq = 0; qq < 4; ++qq) {
            float f0 = bf2f((ushort)a1v[2 * qq])     + bf2f((ushort)(vv[qq] & 0xFFFFu));
            float f1 = bf2f((ushort)a1v[2 * qq + 1]) + bf2f((ushort)(vv[qq] >> 16));
            ov[qq] = cvtpk(fmaxf(f0, 0.f), fmaxf(f1, 0.f));
        }
        *(uint4*)&lds_x[row * 256 + (l0 ^ ((row & 7) << 3))] =
            make_uint4(ov[0], ov[1], ov[2], ov[3]);
    }
    __syncthreads();   // drains vmcnt+lgkm: chunk0 resident in buf0, X ready

    int q = 0;   // linear chunk index li*8+kc
    #pragma unroll 1
    for (int li = 0; li < 3; ++li) {
        f32x4 acc[4][2];
        #pragma unroll
        for (int rt = 0; rt < 4; ++rt)
            #pragma unroll
            for (int ct = 0; ct < 2; ++ct)
                acc[rt][ct] = (f32x4){0.f, 0.f, 0.f, 0.f};

        #pragma unroll 1
        for (int kc = 0; kc < 8; ++kc, ++q) {
            if (q < 23) DMA_CHUNK(q + 1, (q + 1) & 1);
            const ushort* wb = lds_w[q & 1];
            bf16x8 wa[2], xb[4];
            #pragma unroll
            for (int ct = 0; ct < 2; ++ct) {
                int col = col0 + ct * 16 + l15;
                wa[ct] = *(const bf16x8*)
                    &wb[col * 32 + ((lg ^ ((col >> 1) & 3)) << 3)];
            }
            #pragma unroll
            for (int rt = 0; rt < 4; ++rt) {
                int row = rt * 16 + l15;
                xb[rt] = *(const bf16x8*)
                    &lds_x[row * 256 + ((kc * 32 + lg * 8) ^ ((row & 7) << 3))];
            }
            __builtin_amdgcn_s_setprio(1);
            #pragma unroll
            for (int rt = 0; rt < 4; ++rt) {
                acc[rt][0] = MFMA1(wa[0], xb[rt], acc[rt][0]);
                acc[rt][1] = MFMA1(wa[1], xb[rt], acc[rt][1]);
            }
            __builtin_amdgcn_s_setprio(0);
            __syncthreads();   // drains DMA (vmcnt) + read latencies; other block hides it
        }

        const float* bias = (li == 0) ? b2 : (li == 1) ? b3 : b4;
        f32x4 bv[2];
        bv[0] = *(const f32x4*)(bias + col0 + lg * 4);
        bv[1] = *(const f32x4*)(bias + col0 + 16 + lg * 4);

        if (li < 2) {
            // all lds_x reads done (barrier at kc=7); overwrite in place
            #pragma unroll
            for (int rt = 0; rt < 4; ++rt) {
                int row = rt * 16 + l15;
                int sw = (row & 7) << 3;
                #pragma unroll
                for (int ct = 0; ct < 2; ++ct) {
                    f32x4 a = acc[rt][ct];
                    uint2 pk;
                    pk.x = cvtpk(fmaxf(a[0] + bv[ct][0], 0.f),
                                 fmaxf(a[1] + bv[ct][1], 0.f));
                    pk.y = cvtpk(fmaxf(a[2] + bv[ct][2], 0.f),
                                 fmaxf(a[3] + bv[ct][3], 0.f));
                    *(uint2*)&lds_x[row * 256 + ((col0 + ct * 16 + lg * 4) ^ sw)] = pk;
                }
            }
            __syncthreads();
        } else {
            // ---- final layer: reduce over the 64 X-rows; deterministic
            #pragma unroll
            for (int ct = 0; ct < 2; ++ct) {
                f32x4 s = {0.f, 0.f, 0.f, 0.f};
                #pragma unroll
                for (int rt = 0; rt < 4; ++rt) {
                    f32x4 a = acc[rt][ct];
                    s[0] += fmaxf(a[0] + bv[ct][0], 0.f);
                    s[1] += fmaxf(a[1] + bv[ct][1], 0.f);
                    s[2] += fmaxf(a[2] + bv[ct][2], 0.f);
                    s[3] += fmaxf(a[3] + bv[ct][3], 0.f);
                }
                #pragma unroll
                for (int m = 1; m < 16; m <<= 1) {
                    #pragma unroll
                    for (int r = 0; r < 4; ++r) s[r] += __shfl_xor(s[r], m, 64);
                }
                if (l15 == 0) {
                    float4 o = {s[0], s[1], s[2], s[3]};
                    *(float4*)&partial[bi * 256 + col0 + ct * 16 + lg * 4] = o;
                }
            }
        }
    }
}

// ---------------- kernel 4: fused reduce + f-network, one block per b
__global__ __launch_bounds__(256) void kRF(
    const float* __restrict__ partial,
    const float* __restrict__ f_w1, const float* __restrict__ f_b1,
    const float* __restrict__ f_w2, const float* __restrict__ f_b2,
    const float* __restrict__ f_w3, const float* __restrict__ f_b3,
    float* __restrict__ out)
{
    __shared__ float g[256], y1[256], y2[256];
    int b = blockIdx.x, t = threadIdx.x;       // block 256
    {
        float s = 0.f;
        const float* pb = partial + b * 64 * 256 + t;
        #pragma unroll 8
        for (int i = 0; i < 64; ++i) s += pb[i * 256];
        g[t] = s;
    }
    __syncthreads();
    float acc = f_b1[t];
    for (int k = 0; k < 256; ++k) acc += g[k] * f_w1[k * 256 + t];
    y1[t] = fmaxf(acc, 0.f);
    __syncthreads();
    acc = f_b2[t];
    for (int k = 0; k < 256; ++k) acc += y1[k] * f_w2[k * 256 + t];
    y2[t] = fmaxf(acc, 0.f);
    __syncthreads();
    if (t < 100) {
        float o = f_b3[t];
        for (int k = 0; k < 256; ++k) o += y2[k] * f_w3[k * 100 + t];
        out[b * 100 + t] = o;
    }
}

extern "C" void kernel_launch(void* const* d_in, const int* in_sizes, int n_in,
                              void* d_out, int out_size, void* d_ws, size_t ws_size,
                              hipStream_t stream)
{
    const float* box_feats = (const float*)d_in[0];
    const float* emb   = (const float*)d_in[1];
    const float* w_ih  = (const float*)d_in[2];
    const float* w_hh  = (const float*)d_in[3];
    const float* b_ih  = (const float*)d_in[4];
    const float* b_hh  = (const float*)d_in[5];
    const float* g_w1  = (const float*)d_in[6];
    const float* g_b1  = (const float*)d_in[7];
    const float* g_w2  = (const float*)d_in[8];
    const float* g_b2  = (const float*)d_in[9];
    const float* g_w3  = (const float*)d_in[10];
    const float* g_b3  = (const float*)d_in[11];
    const float* g_w4  = (const float*)d_in[12];
    const float* g_b4  = (const float*)d_in[13];
    const float* f_w1  = (const float*)d_in[14];
    const float* f_b1  = (const float*)d_in[15];
    const float* f_w2  = (const float*)d_in[16];
    const float* f_b2  = (const float*)d_in[17];
    const float* f_w3  = (const float*)d_in[18];
    const float* f_b3  = (const float*)d_in[19];
    const int* q_feats = (const int*)d_in[20];
    const int* q_lens  = (const int*)d_in[21];
    float* out = (float*)d_out;

    char* ws = (char*)d_ws;
    float*  P    = (float*) (ws + 0);          //  96*512*4   = 196608
    ushort* A1   = (ushort*)(ws + 196608);     // 8192*256*2  = 4194304
    ushort* A2   = (ushort*)(ws + 4390912);    // 8192*256*2  = 4194304
    ushort* Wst  = (ushort*)(ws + 8585216);    // 3*65536*2   = 393216
    float*  part = (float*) (ws + 8978432);    // 8192*256*4  = 8388608

    hipLaunchKernelGGL(kPW, dim3(120),  dim3(512), 0, stream,
                       emb, w_ih, b_ih, P, g_w2, g_w3, g_w4, Wst);
    hipLaunchKernelGGL(kLA, dim3(128),  dim3(512), 0, stream,
                       P, w_hh, b_hh, g_w1, g_b1, q_feats, q_lens, box_feats, A1, A2);
    hipLaunchKernelGGL(kD,  dim3(8192), dim3(512), 0, stream,
                       A1, A2, Wst, g_b2, g_b3, g_b4, part);
    hipLaunchKernelGGL(kRF, dim3(128),  dim3(256), 0, stream,
                       part, f_w1, f_b1, f_w2, f_b2, f_w3, f_b3, out);
}

// Round 10
// 357.341 us; speedup vs baseline: 1.1641x; 1.0269x over previous
//
#include <hip/hip_runtime.h>
#include <hip/hip_bf16.h>

typedef unsigned int uint;
typedef unsigned short ushort;
typedef __attribute__((ext_vector_type(8))) short bf16x8;
typedef __attribute__((ext_vector_type(4))) float f32x4;

__device__ __forceinline__ float bf2f(ushort u) {
    return __uint_as_float(((uint)u) << 16);
}
__device__ __forceinline__ ushort f2bf(float f) {
    uint u = __float_as_uint(f);
    u += 0x7FFFu + ((u >> 16) & 1u);   // round-to-nearest-even
    return (ushort)(u >> 16);
}
__device__ __forceinline__ uint cvtpk(float lo, float hi) {
    uint r;
    asm("v_cvt_pk_bf16_f32 %0, %1, %2" : "=v"(r) : "v"(lo), "v"(hi));
    return r;
}
__device__ __forceinline__ float sigm(float x) {
    return 1.0f / (1.0f + expf(-x));
}
// async global->LDS DMA, 16 B per lane; lds dest = wave-uniform base + lane*16
__device__ __forceinline__ void dma16(const void* g, void* l) {
    __builtin_amdgcn_global_load_lds(
        (const __attribute__((address_space(1))) void*)g,
        (__attribute__((address_space(3))) void*)l, 16, 0, 0);
}

// ---------------- kernel 1: fused kP (blocks 0-95) + kW (blocks 96-119)
// Wst layout: [li][kc] 16KB chunk = [wave-slice g:8][col&31][k-slot swizzled]
__global__ __launch_bounds__(512) void kPW(
    const float* __restrict__ emb, const float* __restrict__ w_ih,
    const float* __restrict__ b_ih, float* __restrict__ P,
    const float* __restrict__ g_w2, const float* __restrict__ g_w3,
    const float* __restrict__ g_w4, ushort* __restrict__ Wst)
{
    int tid = threadIdx.x;
    if (blockIdx.x < 96) {
        __shared__ __align__(16) float te[300];
        int v = blockIdx.x;
        for (int k = tid; k < 300; k += 512) te[k] = tanhf(emb[v * 300 + k]);
        __syncthreads();
        int g = tid;
        float acc = b_ih[g];
        const float4* wr = (const float4*)(w_ih + g * 300);
        const float4* tv = (const float4*)te;
        for (int k = 0; k < 75; ++k) {
            float4 w4 = wr[k], t4 = tv[k];
            acc += w4.x * t4.x + w4.y * t4.y + w4.z * t4.z + w4.w * t4.w;
        }
        P[v * 512 + g] = acc;
    } else if (tid < 256) {
        int blk = blockIdx.x - 96;
        int li = blk >> 3, kc = blk & 7, col = tid;
        const float* W = (li == 0) ? g_w2 : (li == 1) ? g_w3 : g_w4;
        ushort* dst = Wst + li * 65536 + kc * 8192
                    + (col >> 5) * 1024 + (col & 31) * 32;
        for (int kk = 0; kk < 32; ++kk) {
            int slot = (kk >> 3) ^ ((col >> 1) & 3);
            dst[slot * 8 + (kk & 7)] = f2bf(W[(kc * 32 + kk) * 256 + col]);
        }
    }
}

// ---------------- kernel 2: fused LSTM -> Wq -> A1/A2, 512 threads, 1 gate/thread
#define WROW 132   // padded w_hh row (ushort): 264 B -> 2-way banks on b64 reads
__global__ __launch_bounds__(512) void kLA(
    const float* __restrict__ P, const float* __restrict__ w_hh,
    const float* __restrict__ b_hh, const float* __restrict__ g_w1,
    const float* __restrict__ g_b1, const int* __restrict__ q_feats,
    const int* __restrict__ q_lens, const float* __restrict__ box_feats,
    ushort* __restrict__ A1, ushort* __restrict__ A2)
{
    __shared__ __align__(16) ushort whh[512 * WROW];   // 135168 B
    __shared__ __align__(16) float h[128];
    __shared__ __align__(16) float c[128];
    __shared__ float gates[512];
    __shared__ float wq2[2][256];
    __shared__ float box[64][26];
    int b = blockIdx.x, tid = threadIdx.x;          // block 512
    if (tid < 128) { h[tid] = 0.f; c[tid] = 0.f; }
    for (int i = tid * 4; i < 65536; i += 2048) {
        int g = i >> 7, k = i & 127;
        float4 w4 = *(const float4*)&w_hh[i];
        uint2 o;
        o.x = cvtpk(w4.x, w4.y);
        o.y = cvtpk(w4.z, w4.w);
        *(uint2*)&whh[g * WROW + k] = o;
    }
    for (int idx = tid; idx < 64 * 26; idx += 512) {
        int n = idx / 26, d = idx - n * 26;
        float v;
        if (d < 24)       v = box_feats[(b * 64 + n) * 24 + d];
        else if (d == 24) v = ((n >> 3) - 4) * 0.125f;
        else              v = ((n & 7) - 4) * 0.125f;
        box[n][d] = v;
    }
    __syncthreads();
    int len = q_lens[b];
    const int g = tid;
    const ushort* wr = &whh[g * WROW];
    for (int t = 0; t < len; ++t) {
        int idx = q_feats[b * 20 + t];
        float acc = P[idx * 512 + g] + b_hh[g];
        #pragma unroll
        for (int k8 = 0; k8 < 16; ++k8) {
            uint2 wlo = *(const uint2*)&wr[k8 * 8];
            uint2 whi = *(const uint2*)&wr[k8 * 8 + 4];
            float4 h0 = *(const float4*)&h[k8 * 8];
            float4 h1 = *(const float4*)&h[k8 * 8 + 4];
            acc += bf2f((ushort)(wlo.x & 0xFFFFu)) * h0.x
                 + bf2f((ushort)(wlo.x >> 16))     * h0.y
                 + bf2f((ushort)(wlo.y & 0xFFFFu)) * h0.z
                 + bf2f((ushort)(wlo.y >> 16))     * h0.w
                 + bf2f((ushort)(whi.x & 0xFFFFu)) * h1.x
                 + bf2f((ushort)(whi.x >> 16))     * h1.y
                 + bf2f((ushort)(whi.y & 0xFFFFu)) * h1.z
                 + bf2f((ushort)(whi.y >> 16))     * h1.w;
        }
        gates[g] = acc;
        __syncthreads();
        if (tid < 128) {
            float ig = sigm(gates[tid]);
            float fg = sigm(gates[128 + tid]);
            float gg = tanhf(gates[256 + tid]);
            float og = sigm(gates[384 + tid]);
            float cn = fg * c[tid] + ig * gg;
            c[tid] = cn;
            h[tid] = og * tanhf(cn);
        }
        __syncthreads();
    }
    {
        int l = tid & 255, half = tid >> 8;
        float acc = (half == 0) ? g_b1[l] : 0.f;
        for (int k = 0; k < 64; ++k)
            acc += c[half * 64 + k] * g_w1[(52 + half * 64 + k) * 256 + l];
        wq2[half][l] = acc;
    }
    __syncthreads();
    {
        int l = tid & 255, n0 = tid >> 8;
        float w1a[26], w1b[26];
        #pragma unroll
        for (int d = 0; d < 26; ++d) {
            w1a[d] = g_w1[d * 256 + l];
            w1b[d] = g_w1[(26 + d) * 256 + l];
        }
        float wqv = wq2[0][l] + wq2[1][l];
        for (int n = n0; n < 64; n += 2) {
            float a1 = 0.f, a2 = wqv;
            #pragma unroll
            for (int d = 0; d < 26; ++d) {
                a1 += box[n][d] * w1a[d];
                a2 += box[n][d] * w1b[d];
            }
            A1[(b * 64 + n) * 256 + l] = f2bf(a1);
            A2[(b * 64 + n) * 256 + l] = f2bf(a2);
        }
    }
}

// ---------------- kernel 3: pair-MLP; per-wave private W slices, barrier-free K-loop
#define MFMA1(wa, xb, a) __builtin_amdgcn_mfma_f32_16x16x32_bf16(wa, xb, a, 0, 0, 0)

// stage chunk Q's 2KB slice for wave wv into its private buffer (parity Q&1)
#define DMA2(Q)                                                                 \
    do {                                                                        \
        const char* gs_ = (const char*)Wst + (Q) * 16384 + wv * 2048 + (lane << 4); \
        char* ls_ = (char*)&lds_w[(Q) & 1][wv][0];                              \
        dma16(gs_, ls_);                                                        \
        dma16(gs_ + 1024, ls_ + 1024);                                          \
    } while (0)

__global__ __launch_bounds__(512, 2) void kD(
    const ushort* __restrict__ A1, const ushort* __restrict__ A2,
    const ushort* __restrict__ Wst,
    const float* __restrict__ b2, const float* __restrict__ b3,
    const float* __restrict__ b4, float* __restrict__ partial)
{
    __shared__ __align__(16) ushort lds_x[256 * 256];     // 131072 B, XOR-swizzled rows
    __shared__ __align__(16) ushort lds_w[2][8][1024];    // [parity][wave][2KB] = 32768 B

    const int tid = threadIdx.x;
    const int b = blockIdx.x >> 4, iblk = blockIdx.x & 15;   // 4 pairs: i = iblk*4+p
    const int lane = tid & 63, wv = tid >> 6;                // 8 waves
    const int l15 = lane & 15, lg = lane >> 4;
    const int col0 = wv * 32;          // wave tile: 256 rows x 32 EXCLUSIVE cols

    // prime the private DMA pipeline: chunks 0 and 1 in flight
    DMA2(0);
    DMA2(1);

    // ---- a1 rows in registers (transient)
    const int l0 = (tid & 31) << 3;
    bf16x8 a1r[4];
    #pragma unroll
    for (int p = 0; p < 4; ++p)
        a1r[p] = *(const bf16x8*)&A1[(b * 64 + iblk * 4 + p) * 256 + l0];

    // ---- build X1 (swizzled): X[p*64+j][l] = relu(a1[p][l] + A2[b,j][l])
    const ushort* A2b = A2 + b * 64 * 256;
    #pragma unroll
    for (int p8 = 0; p8 < 16; ++p8) {
        int row = p8 * 16 + (tid >> 5);        // 0..255 each exactly once
        int j = row & 63;
        uint4 v = *(const uint4*)(A2b + j * 256 + l0);
        bf16x8 a1v = a1r[p8 >> 2];             // row>>6 == p8>>2 (compile-time)
        uint vv[4] = {v.x, v.y, v.z, v.w}, ov[4];
        #pragma unroll
        for (int qq = 0; qq < 4; ++qq) {
            float f0 = bf2f((ushort)a1v[2 * qq])     + bf2f((ushort)(vv[qq] & 0xFFFFu));
            float f1 = bf2f((ushort)a1v[2 * qq + 1]) + bf2f((ushort)(vv[qq] >> 16));
            ov[qq] = cvtpk(fmaxf(f0, 0.f), fmaxf(f1, 0.f));
        }
        *(uint4*)&lds_x[row * 256 + (l0 ^ ((row & 7) << 3))] =
            make_uint4(ov[0], ov[1], ov[2], ov[3]);
    }
    // X visible to all; do NOT drain vmcnt (DMA 0/1 stay in flight; FIFO order
    // guarantees they complete before the A2 loads the compiler already waited on)
    asm volatile("s_waitcnt lgkmcnt(0)" ::: "memory");
    __builtin_amdgcn_sched_barrier(0);
    __builtin_amdgcn_s_barrier();

    #pragma unroll 1
    for (int li = 0; li < 3; ++li) {
        f32x4 acc[16][2];
        #pragma unroll
        for (int rt = 0; rt < 16; ++rt) {
            acc[rt][0] = (f32x4){0.f, 0.f, 0.f, 0.f};
            acc[rt][1] = (f32x4){0.f, 0.f, 0.f, 0.f};
        }

        // ---- barrier-free K-loop: 8 chunks, private W dbuf, counted vmcnt
        #pragma unroll
        for (int kc = 0; kc < 8; ++kc) {
            const ushort* wb = &lds_w[kc & 1][wv][0];
            int c5a = l15, c5b = 16 + l15;
            bf16x8 wa0 = *(const bf16x8*)
                &wb[c5a * 32 + ((lg ^ ((c5a >> 1) & 3)) << 3)];
            bf16x8 wa1 = *(const bf16x8*)
                &wb[c5b * 32 + ((lg ^ ((c5b >> 1) & 3)) << 3)];
            bf16x8 xb[16];
            #pragma unroll
            for (int rt = 0; rt < 16; ++rt) {
                int row = rt * 16 + l15;
                xb[rt] = *(const bf16x8*)
                    &lds_x[row * 256 + ((kc * 32 + lg * 8) ^ ((row & 7) << 3))];
            }
            __builtin_amdgcn_s_setprio(1);
            #pragma unroll
            for (int rt = 0; rt < 16; ++rt) {
                acc[rt][0] = MFMA1(wa0, xb[rt], acc[rt][0]);
                acc[rt][1] = MFMA1(wa1, xb[rt], acc[rt][1]);
            }
            __builtin_amdgcn_s_setprio(0);
            __builtin_amdgcn_sched_barrier(0);   // reads consumed; now recycle buffer
            if (li * 8 + kc < 22) {
                DMA2(li * 8 + kc + 2);
                asm volatile("s_waitcnt vmcnt(2)" ::: "memory");   // chunk q+1 landed
            } else {
                asm volatile("s_waitcnt vmcnt(0)" ::: "memory");   // tail drain
            }
            __builtin_amdgcn_sched_barrier(0);
        }

        const float* bias = (li == 0) ? b2 : (li == 1) ? b3 : b4;
        f32x4 bv0 = *(const f32x4*)(bias + col0 + lg * 4);
        f32x4 bv1 = *(const f32x4*)(bias + col0 + 16 + lg * 4);

        if (li < 2) {
            __builtin_amdgcn_s_barrier();   // all waves done reading lds_x
            #pragma unroll
            for (int rt = 0; rt < 16; ++rt) {
                int row = rt * 16 + l15;
                int sw = (row & 7) << 3;
                f32x4 a0 = acc[rt][0], a1 = acc[rt][1];
                uint2 pk0, pk1;
                pk0.x = cvtpk(fmaxf(a0[0] + bv0[0], 0.f), fmaxf(a0[1] + bv0[1], 0.f));
                pk0.y = cvtpk(fmaxf(a0[2] + bv0[2], 0.f), fmaxf(a0[3] + bv0[3], 0.f));
                pk1.x = cvtpk(fmaxf(a1[0] + bv1[0], 0.f), fmaxf(a1[1] + bv1[1], 0.f));
                pk1.y = cvtpk(fmaxf(a1[2] + bv1[2], 0.f), fmaxf(a1[3] + bv1[3], 0.f));
                *(uint2*)&lds_x[row * 256 + ((col0 + lg * 4) ^ sw)] = pk0;
                *(uint2*)&lds_x[row * 256 + ((col0 + 16 + lg * 4) ^ sw)] = pk1;
            }
            asm volatile("s_waitcnt lgkmcnt(0)" ::: "memory");
            __builtin_amdgcn_sched_barrier(0);
            __builtin_amdgcn_s_barrier();   // new X visible to all
        } else {
            // ---- final layer: per pair p (rows 64p..64p+63 = rt 4p..4p+3)
            #pragma unroll
            for (int p = 0; p < 4; ++p) {
                f32x4 s0 = {0.f, 0.f, 0.f, 0.f}, s1 = {0.f, 0.f, 0.f, 0.f};
                #pragma unroll
                for (int r = 0; r < 4; ++r) {
                    f32x4 a0 = acc[p * 4 + r][0], a1 = acc[p * 4 + r][1];
                    s0[0] += fmaxf(a0[0] + bv0[0], 0.f);
                    s0[1] += fmaxf(a0[1] + bv0[1], 0.f);
                    s0[2] += fmaxf(a0[2] + bv0[2], 0.f);
                    s0[3] += fmaxf(a0[3] + bv0[3], 0.f);
                    s1[0] += fmaxf(a1[0] + bv1[0], 0.f);
                    s1[1] += fmaxf(a1[1] + bv1[1], 0.f);
                    s1[2] += fmaxf(a1[2] + bv1[2], 0.f);
                    s1[3] += fmaxf(a1[3] + bv1[3], 0.f);
                }
                #pragma unroll
                for (int m = 1; m < 16; m <<= 1) {
                    #pragma unroll
                    for (int r = 0; r < 4; ++r) {
                        s0[r] += __shfl_xor(s0[r], m, 64);
                        s1[r] += __shfl_xor(s1[r], m, 64);
                    }
                }
                if (l15 == 0) {
                    int prow = b * 64 + iblk * 4 + p;
                    float4 o0 = {s0[0], s0[1], s0[2], s0[3]};
                    float4 o1 = {s1[0], s1[1], s1[2], s1[3]};
                    *(float4*)&partial[prow * 256 + col0 + lg * 4] = o0;
                    *(float4*)&partial[prow * 256 + col0 + 16 + lg * 4] = o1;
                }
            }
        }
    }
}

// ---------------- kernel 4: fused reduce + f-network, one block per b
__global__ __launch_bounds__(256) void kRF(
    const float* __restrict__ partial,
    const float* __restrict__ f_w1, const float* __restrict__ f_b1,
    const float* __restrict__ f_w2, const float* __restrict__ f_b2,
    const float* __restrict__ f_w3, const float* __restrict__ f_b3,
    float* __restrict__ out)
{
    __shared__ float g[256], y1[256], y2[256];
    int b = blockIdx.x, t = threadIdx.x;       // block 256
    {
        float s = 0.f;
        const float* pb = partial + b * 64 * 256 + t;
        #pragma unroll 8
        for (int i = 0; i < 64; ++i) s += pb[i * 256];
        g[t] = s;
    }
    __syncthreads();
    float acc = f_b1[t];
    for (int k = 0; k < 256; ++k) acc += g[k] * f_w1[k * 256 + t];
    y1[t] = fmaxf(acc, 0.f);
    __syncthreads();
    acc = f_b2[t];
    for (int k = 0; k < 256; ++k) acc += y1[k] * f_w2[k * 256 + t];
    y2[t] = fmaxf(acc, 0.f);
    __syncthreads();
    if (t < 100) {
        float o = f_b3[t];
        for (int k = 0; k < 256; ++k) o += y2[k] * f_w3[k * 100 + t];
        out[b * 100 + t] = o;
    }
}

extern "C" void kernel_launch(void* const* d_in, const int* in_sizes, int n_in,
                              void* d_out, int out_size, void* d_ws, size_t ws_size,
                              hipStream_t stream)
{
    const float* box_feats = (const float*)d_in[0];
    const float* emb   = (const float*)d_in[1];
    const float* w_ih  = (const float*)d_in[2];
    const float* w_hh  = (const float*)d_in[3];
    const float* b_ih  = (const float*)d_in[4];
    const float* b_hh  = (const float*)d_in[5];
    const float* g_w1  = (const float*)d_in[6];
    const float* g_b1  = (const float*)d_in[7];
    const float* g_w2  = (const float*)d_in[8];
    const float* g_b2  = (const float*)d_in[9];
    const float* g_w3  = (const float*)d_in[10];
    const float* g_b3  = (const float*)d_in[11];
    const float* g_w4  = (const float*)d_in[12];
    const float* g_b4  = (const float*)d_in[13];
    const float* f_w1  = (const float*)d_in[14];
    const float* f_b1  = (const float*)d_in[15];
    const float* f_w2  = (const float*)d_in[16];
    const float* f_b2  = (const float*)d_in[17];
    const float* f_w3  = (const float*)d_in[18];
    const float* f_b3  = (const float*)d_in[19];
    const int* q_feats = (const int*)d_in[20];
    const int* q_lens  = (const int*)d_in[21];
    float* out = (float*)d_out;

    char* ws = (char*)d_ws;
    float*  P    = (float*) (ws + 0);          //  96*512*4   = 196608
    ushort* A1   = (ushort*)(ws + 196608);     // 8192*256*2  = 4194304
    ushort* A2   = (ushort*)(ws + 4390912);    // 8192*256*2  = 4194304
    ushort* Wst  = (ushort*)(ws + 8585216);    // 3*65536*2   = 393216
    float*  part = (float*) (ws + 8978432);    // 8192*256*4  = 8388608

    hipLaunchKernelGGL(kPW, dim3(120),  dim3(512), 0, stream,
                       emb, w_ih, b_ih, P, g_w2, g_w3, g_w4, Wst);
    hipLaunchKernelGGL(kLA, dim3(128),  dim3(512), 0, stream,
                       P, w_hh, b_hh, g_w1, g_b1, q_feats, q_lens, box_feats, A1, A2);
    hipLaunchKernelGGL(kD,  dim3(2048), dim3(512), 0, stream,
                       A1, A2, Wst, g_b2, g_b3, g_b4, part);
    hipLaunchKernelGGL(kRF, dim3(128),  dim3(256), 0, stream,
                       part, f_w1, f_b1, f_w2, f_b2, f_w3, f_b3, out);
}

// Round 11
// 288.606 us; speedup vs baseline: 1.4413x; 1.2382x over previous
//
#include <hip/hip_runtime.h>
#include <hip/hip_bf16.h>

typedef unsigned int uint;
typedef unsigned short ushort;
typedef __attribute__((ext_vector_type(8))) short bf16x8;
typedef __attribute__((ext_vector_type(4))) float f32x4;

__device__ __forceinline__ float bf2f(ushort u) {
    return __uint_as_float(((uint)u) << 16);
}
__device__ __forceinline__ ushort f2bf(float f) {
    uint u = __float_as_uint(f);
    u += 0x7FFFu + ((u >> 16) & 1u);   // round-to-nearest-even
    return (ushort)(u >> 16);
}
__device__ __forceinline__ uint cvtpk(float lo, float hi) {
    uint r;
    asm("v_cvt_pk_bf16_f32 %0, %1, %2" : "=v"(r) : "v"(lo), "v"(hi));
    return r;
}
__device__ __forceinline__ float sigm(float x) {
    return 1.0f / (1.0f + expf(-x));
}

// ---------------- kernel 1: fused kP (blocks 0-95) + kW (blocks 96-119)
// Wst layout (per li,kc 16KB chunk): [colgrp:16][kslot:4][col&15:16][8]
// -> one wave reading {16 cols x 8 k-elems} = contiguous 1KB, lane-order.
__global__ __launch_bounds__(512) void kPW(
    const float* __restrict__ emb, const float* __restrict__ w_ih,
    const float* __restrict__ b_ih, float* __restrict__ P,
    const float* __restrict__ g_w2, const float* __restrict__ g_w3,
    const float* __restrict__ g_w4, ushort* __restrict__ Wst)
{
    int tid = threadIdx.x;
    if (blockIdx.x < 96) {
        __shared__ __align__(16) float te[300];
        int v = blockIdx.x;
        for (int k = tid; k < 300; k += 512) te[k] = tanhf(emb[v * 300 + k]);
        __syncthreads();
        int g = tid;
        float acc = b_ih[g];
        const float4* wr = (const float4*)(w_ih + g * 300);
        const float4* tv = (const float4*)te;
        for (int k = 0; k < 75; ++k) {
            float4 w4 = wr[k], t4 = tv[k];
            acc += w4.x * t4.x + w4.y * t4.y + w4.z * t4.z + w4.w * t4.w;
        }
        P[v * 512 + g] = acc;
    } else if (tid < 256) {
        int blk = blockIdx.x - 96;
        int li = blk >> 3, kc = blk & 7, col = tid;
        const float* W = (li == 0) ? g_w2 : (li == 1) ? g_w3 : g_w4;
        ushort* dst = Wst + li * 65536 + kc * 8192
                    + (col >> 4) * 512 + (col & 15) * 8;
        for (int kk = 0; kk < 32; ++kk)
            dst[(kk >> 3) * 128 + (kk & 7)] = f2bf(W[(kc * 32 + kk) * 256 + col]);
    }
}

// ---------------- kernel 2: fused LSTM -> Wq -> A1/A2, 512 threads, 1 gate/thread
#define WROW 132   // padded w_hh row (ushort): 264 B -> 2-way banks on b64 reads
__global__ __launch_bounds__(512) void kLA(
    const float* __restrict__ P, const float* __restrict__ w_hh,
    const float* __restrict__ b_hh, const float* __restrict__ g_w1,
    const float* __restrict__ g_b1, const int* __restrict__ q_feats,
    const int* __restrict__ q_lens, const float* __restrict__ box_feats,
    ushort* __restrict__ A1, ushort* __restrict__ A2)
{
    __shared__ __align__(16) ushort whh[512 * WROW];   // 135168 B
    __shared__ __align__(16) float h[128];
    __shared__ __align__(16) float c[128];
    __shared__ float gates[512];
    __shared__ float wq2[2][256];
    __shared__ float box[64][26];
    int b = blockIdx.x, tid = threadIdx.x;          // block 512
    if (tid < 128) { h[tid] = 0.f; c[tid] = 0.f; }
    for (int i = tid * 4; i < 65536; i += 2048) {
        int g = i >> 7, k = i & 127;
        float4 w4 = *(const float4*)&w_hh[i];
        uint2 o;
        o.x = cvtpk(w4.x, w4.y);
        o.y = cvtpk(w4.z, w4.w);
        *(uint2*)&whh[g * WROW + k] = o;
    }
    for (int idx = tid; idx < 64 * 26; idx += 512) {
        int n = idx / 26, d = idx - n * 26;
        float v;
        if (d < 24)       v = box_feats[(b * 64 + n) * 24 + d];
        else if (d == 24) v = ((n >> 3) - 4) * 0.125f;
        else              v = ((n & 7) - 4) * 0.125f;
        box[n][d] = v;
    }
    __syncthreads();
    int len = q_lens[b];
    const int g = tid;
    const ushort* wr = &whh[g * WROW];
    for (int t = 0; t < len; ++t) {
        int idx = q_feats[b * 20 + t];
        float acc = P[idx * 512 + g] + b_hh[g];
        #pragma unroll
        for (int k8 = 0; k8 < 16; ++k8) {
            uint2 wlo = *(const uint2*)&wr[k8 * 8];
            uint2 whi = *(const uint2*)&wr[k8 * 8 + 4];
            float4 h0 = *(const float4*)&h[k8 * 8];
            float4 h1 = *(const float4*)&h[k8 * 8 + 4];
            acc += bf2f((ushort)(wlo.x & 0xFFFFu)) * h0.x
                 + bf2f((ushort)(wlo.x >> 16))     * h0.y
                 + bf2f((ushort)(wlo.y & 0xFFFFu)) * h0.z
                 + bf2f((ushort)(wlo.y >> 16))     * h0.w
                 + bf2f((ushort)(whi.x & 0xFFFFu)) * h1.x
                 + bf2f((ushort)(whi.x >> 16))     * h1.y
                 + bf2f((ushort)(whi.y & 0xFFFFu)) * h1.z
                 + bf2f((ushort)(whi.y >> 16))     * h1.w;
        }
        gates[g] = acc;
        __syncthreads();
        if (tid < 128) {
            float ig = sigm(gates[tid]);
            float fg = sigm(gates[128 + tid]);
            float gg = tanhf(gates[256 + tid]);
            float og = sigm(gates[384 + tid]);
            float cn = fg * c[tid] + ig * gg;
            c[tid] = cn;
            h[tid] = og * tanhf(cn);
        }
        __syncthreads();
    }
    {
        int l = tid & 255, half = tid >> 8;
        float acc = (half == 0) ? g_b1[l] : 0.f;
        for (int k = 0; k < 64; ++k)
            acc += c[half * 64 + k] * g_w1[(52 + half * 64 + k) * 256 + l];
        wq2[half][l] = acc;
    }
    __syncthreads();
    {
        int l = tid & 255, n0 = tid >> 8;
        float w1a[26], w1b[26];
        #pragma unroll
        for (int d = 0; d < 26; ++d) {
            w1a[d] = g_w1[d * 256 + l];
            w1b[d] = g_w1[(26 + d) * 256 + l];
        }
        float wqv = wq2[0][l] + wq2[1][l];
        for (int n = n0; n < 64; n += 2) {
            float a1 = 0.f, a2 = wqv;
            #pragma unroll
            for (int d = 0; d < 26; ++d) {
                a1 += box[n][d] * w1a[d];
                a2 += box[n][d] * w1b[d];
            }
            A1[(b * 64 + n) * 256 + l] = f2bf(a1);
            A2[(b * 64 + n) * 256 + l] = f2bf(a2);
        }
    }
}

// ---------------- kernel 3: pair-MLP; W from L2 (no W-LDS), barrier-free K-loop
#define MFMA1(wa, xb, a) __builtin_amdgcn_mfma_f32_16x16x32_bf16(wa, xb, a, 0, 0, 0)

__global__ __launch_bounds__(512, 2) void kD(
    const ushort* __restrict__ A1, const ushort* __restrict__ A2,
    const ushort* __restrict__ Wst,
    const float* __restrict__ b2, const float* __restrict__ b3,
    const float* __restrict__ b4, float* __restrict__ partial)
{
    __shared__ __align__(16) ushort lds_x[256 * 256];   // 131072 B, XOR-swizzled rows

    const int tid = threadIdx.x;
    const int b = blockIdx.x >> 4, iblk = blockIdx.x & 15;   // 4 pairs: i = iblk*4+p
    const int lane = tid & 63, wv = tid >> 6;                // 8 waves
    const int l15 = lane & 15, lg = lane >> 4;
    const int wrow0 = (wv & 1) * 128, col0 = (wv >> 1) * 64; // wave tile 128r x 64c

    // ---- a1 rows in registers (transient)
    const int l0 = (tid & 31) << 3;
    bf16x8 a1r[4];
    #pragma unroll
    for (int p = 0; p < 4; ++p)
        a1r[p] = *(const bf16x8*)&A1[(b * 64 + iblk * 4 + p) * 256 + l0];

    // ---- build X1 (swizzled): X[p*64+j][l] = relu(a1[p][l] + A2[b,j][l])
    const ushort* A2b = A2 + b * 64 * 256;
    #pragma unroll
    for (int p8 = 0; p8 < 16; ++p8) {
        int row = p8 * 16 + (tid >> 5);        // 0..255 each exactly once
        int j = row & 63;
        uint4 v = *(const uint4*)(A2b + j * 256 + l0);
        bf16x8 a1v = a1r[p8 >> 2];             // row>>6 == p8>>2 (compile-time)
        uint vv[4] = {v.x, v.y, v.z, v.w}, ov[4];
        #pragma unroll
        for (int qq = 0; qq < 4; ++qq) {
            float f0 = bf2f((ushort)a1v[2 * qq])     + bf2f((ushort)(vv[qq] & 0xFFFFu));
            float f1 = bf2f((ushort)a1v[2 * qq + 1]) + bf2f((ushort)(vv[qq] >> 16));
            ov[qq] = cvtpk(fmaxf(f0, 0.f), fmaxf(f1, 0.f));
        }
        *(uint4*)&lds_x[row * 256 + (l0 ^ ((row & 7) << 3))] =
            make_uint4(ov[0], ov[1], ov[2], ov[3]);
    }
    __syncthreads();   // X ready

    // per-lane W base: this wave's 4 col-groups start at (col0>>4)*1KB; lane*16B
    const char* wbase = (const char*)Wst + (col0 >> 4) * 1024 + lane * 16;

    #pragma unroll 1
    for (int li = 0; li < 3; ++li) {
        f32x4 acc[8][4];
        #pragma unroll
        for (int rt = 0; rt < 8; ++rt)
            #pragma unroll
            for (int ct = 0; ct < 4; ++ct)
                acc[rt][ct] = (f32x4){0.f, 0.f, 0.f, 0.f};

        // ---- barrier-free K-loop: W straight from L2, X from LDS (read-only)
        #pragma unroll 1
        for (int kc = 0; kc < 8; ++kc) {
            const char* wp = wbase + li * 131072 + kc * 16384;
            bf16x8 wa0 = *(const bf16x8*)(wp);
            bf16x8 wa1 = *(const bf16x8*)(wp + 1024);
            bf16x8 wa2 = *(const bf16x8*)(wp + 2048);
            bf16x8 wa3 = *(const bf16x8*)(wp + 3072);
            bf16x8 xb[8];
            #pragma unroll
            for (int rt = 0; rt < 8; ++rt) {
                int row = wrow0 + rt * 16 + l15;
                xb[rt] = *(const bf16x8*)
                    &lds_x[row * 256 + ((kc * 32 + lg * 8) ^ ((row & 7) << 3))];
            }
            __builtin_amdgcn_s_setprio(1);
            #pragma unroll
            for (int rt = 0; rt < 8; ++rt) {
                acc[rt][0] = MFMA1(wa0, xb[rt], acc[rt][0]);
                acc[rt][1] = MFMA1(wa1, xb[rt], acc[rt][1]);
                acc[rt][2] = MFMA1(wa2, xb[rt], acc[rt][2]);
                acc[rt][3] = MFMA1(wa3, xb[rt], acc[rt][3]);
            }
            __builtin_amdgcn_s_setprio(0);
        }

        const float* bias = (li == 0) ? b2 : (li == 1) ? b3 : b4;
        f32x4 bv0 = *(const f32x4*)(bias + col0 + lg * 4);
        f32x4 bv1 = *(const f32x4*)(bias + col0 + 16 + lg * 4);
        f32x4 bv2 = *(const f32x4*)(bias + col0 + 32 + lg * 4);
        f32x4 bv3 = *(const f32x4*)(bias + col0 + 48 + lg * 4);

        if (li < 2) {
            __builtin_amdgcn_s_barrier();   // all waves done reading lds_x this layer
            #pragma unroll
            for (int rt = 0; rt < 8; ++rt) {
                int row = wrow0 + rt * 16 + l15;
                int sw = (row & 7) << 3;
                #pragma unroll
                for (int ct = 0; ct < 4; ++ct) {
                    f32x4 a = acc[rt][ct];
                    f32x4 bv = (ct == 0) ? bv0 : (ct == 1) ? bv1 : (ct == 2) ? bv2 : bv3;
                    uint2 pk;
                    pk.x = cvtpk(fmaxf(a[0] + bv[0], 0.f), fmaxf(a[1] + bv[1], 0.f));
                    pk.y = cvtpk(fmaxf(a[2] + bv[2], 0.f), fmaxf(a[3] + bv[3], 0.f));
                    *(uint2*)&lds_x[row * 256 + ((col0 + ct * 16 + lg * 4) ^ sw)] = pk;
                }
            }
            asm volatile("s_waitcnt lgkmcnt(0)" ::: "memory");
            __builtin_amdgcn_sched_barrier(0);
            __builtin_amdgcn_s_barrier();   // new X visible to all
        } else {
            // ---- final layer: reduce 2x64 rows per wave; deterministic
            #pragma unroll
            for (int ct = 0; ct < 4; ++ct) {
                f32x4 bv = (ct == 0) ? bv0 : (ct == 1) ? bv1 : (ct == 2) ? bv2 : bv3;
                f32x4 s0 = {0.f, 0.f, 0.f, 0.f}, s1 = {0.f, 0.f, 0.f, 0.f};
                #pragma unroll
                for (int rt = 0; rt < 4; ++rt) {
                    f32x4 a = acc[rt][ct];
                    s0[0] += fmaxf(a[0] + bv[0], 0.f); s0[1] += fmaxf(a[1] + bv[1], 0.f);
                    s0[2] += fmaxf(a[2] + bv[2], 0.f); s0[3] += fmaxf(a[3] + bv[3], 0.f);
                }
                #pragma unroll
                for (int rt = 4; rt < 8; ++rt) {
                    f32x4 a = acc[rt][ct];
                    s1[0] += fmaxf(a[0] + bv[0], 0.f); s1[1] += fmaxf(a[1] + bv[1], 0.f);
                    s1[2] += fmaxf(a[2] + bv[2], 0.f); s1[3] += fmaxf(a[3] + bv[3], 0.f);
                }
                #pragma unroll
                for (int m = 1; m < 16; m <<= 1) {
                    #pragma unroll
                    for (int r = 0; r < 4; ++r) {
                        s0[r] += __shfl_xor(s0[r], m, 64);
                        s1[r] += __shfl_xor(s1[r], m, 64);
                    }
                }
                if (l15 == 0) {
                    int prow = b * 64 + iblk * 4 + (wv & 1) * 2;
                    float4 o0 = {s0[0], s0[1], s0[2], s0[3]};
                    float4 o1 = {s1[0], s1[1], s1[2], s1[3]};
                    *(float4*)&partial[(prow    ) * 256 + col0 + ct * 16 + lg * 4] = o0;
                    *(float4*)&partial[(prow + 1) * 256 + col0 + ct * 16 + lg * 4] = o1;
                }
            }
        }
    }
}

// ---------------- kernel 4: fused reduce + f-network, one block per b
__global__ __launch_bounds__(256) void kRF(
    const float* __restrict__ partial,
    const float* __restrict__ f_w1, const float* __restrict__ f_b1,
    const float* __restrict__ f_w2, const float* __restrict__ f_b2,
    const float* __restrict__ f_w3, const float* __restrict__ f_b3,
    float* __restrict__ out)
{
    __shared__ float g[256], y1[256], y2[256];
    int b = blockIdx.x, t = threadIdx.x;       // block 256
    {
        float s = 0.f;
        const float* pb = partial + b * 64 * 256 + t;
        #pragma unroll 8
        for (int i = 0; i < 64; ++i) s += pb[i * 256];
        g[t] = s;
    }
    __syncthreads();
    float acc = f_b1[t];
    for (int k = 0; k < 256; ++k) acc += g[k] * f_w1[k * 256 + t];
    y1[t] = fmaxf(acc, 0.f);
    __syncthreads();
    acc = f_b2[t];
    for (int k = 0; k < 256; ++k) acc += y1[k] * f_w2[k * 256 + t];
    y2[t] = fmaxf(acc, 0.f);
    __syncthreads();
    if (t < 100) {
        float o = f_b3[t];
        for (int k = 0; k < 256; ++k) o += y2[k] * f_w3[k * 100 + t];
        out[b * 100 + t] = o;
    }
}

extern "C" void kernel_launch(void* const* d_in, const int* in_sizes, int n_in,
                              void* d_out, int out_size, void* d_ws, size_t ws_size,
                              hipStream_t stream)
{
    const float* box_feats = (const float*)d_in[0];
    const float* emb   = (const float*)d_in[1];
    const float* w_ih  = (const float*)d_in[2];
    const float* w_hh  = (const float*)d_in[3];
    const float* b_ih  = (const float*)d_in[4];
    const float* b_hh  = (const float*)d_in[5];
    const float* g_w1  = (const float*)d_in[6];
    const float* g_b1  = (const float*)d_in[7];
    const float* g_w2  = (const float*)d_in[8];
    const float* g_b2  = (const float*)d_in[9];
    const float* g_w3  = (const float*)d_in[10];
    const float* g_b3  = (const float*)d_in[11];
    const float* g_w4  = (const float*)d_in[12];
    const float* g_b4  = (const float*)d_in[13];
    const float* f_w1  = (const float*)d_in[14];
    const float* f_b1  = (const float*)d_in[15];
    const float* f_w2  = (const float*)d_in[16];
    const float* f_b2  = (const float*)d_in[17];
    const float* f_w3  = (const float*)d_in[18];
    const float* f_b3  = (const float*)d_in[19];
    const int* q_feats = (const int*)d_in[20];
    const int* q_lens  = (const int*)d_in[21];
    float* out = (float*)d_out;

    char* ws = (char*)d_ws;
    float*  P    = (float*) (ws + 0);          //  96*512*4   = 196608
    ushort* A1   = (ushort*)(ws + 196608);     // 8192*256*2  = 4194304
    ushort* A2   = (ushort*)(ws + 4390912);    // 8192*256*2  = 4194304
    ushort* Wst  = (ushort*)(ws + 8585216);    // 3*65536*2   = 393216
    float*  part = (float*) (ws + 8978432);    // 8192*256*4  = 8388608

    hipLaunchKernelGGL(kPW, dim3(120),  dim3(512), 0, stream,
                       emb, w_ih, b_ih, P, g_w2, g_w3, g_w4, Wst);
    hipLaunchKernelGGL(kLA, dim3(128),  dim3(512), 0, stream,
                       P, w_hh, b_hh, g_w1, g_b1, q_feats, q_lens, box_feats, A1, A2);
    hipLaunchKernelGGL(kD,  dim3(2048), dim3(512), 0, stream,
                       A1, A2, Wst, g_b2, g_b3, g_b4, part);
    hipLaunchKernelGGL(kRF, dim3(128),  dim3(256), 0, stream,
                       part, f_w1, f_b1, f_w2, f_b2, f_w3, f_b3, out);
}

// Round 12
// 279.547 us; speedup vs baseline: 1.4880x; 1.0324x over previous
//
#include <hip/hip_runtime.h>
#include <hip/hip_bf16.h>

typedef unsigned int uint;
typedef unsigned short ushort;
typedef __attribute__((ext_vector_type(8))) short bf16x8;
typedef __attribute__((ext_vector_type(4))) float f32x4;

__device__ __forceinline__ float bf2f(ushort u) {
    return __uint_as_float(((uint)u) << 16);
}
__device__ __forceinline__ ushort f2bf(float f) {
    uint u = __float_as_uint(f);
    u += 0x7FFFu + ((u >> 16) & 1u);   // round-to-nearest-even
    return (ushort)(u >> 16);
}
__device__ __forceinline__ uint cvtpk(float lo, float hi) {
    uint r;
    asm("v_cvt_pk_bf16_f32 %0, %1, %2" : "=v"(r) : "v"(lo), "v"(hi));
    return r;
}
__device__ __forceinline__ float sigm(float x) {
    return 1.0f / (1.0f + expf(-x));
}

// ---------------- kernel 1: fused kP (blocks 0-95) + kW (blocks 96-119)
// Wst layout (per li,kc 16KB chunk): [colgrp:16][kslot:4][col&15:16][8]
// -> one wave reading {16 cols x 8 k-elems} = contiguous 1KB, lane-order.
__global__ __launch_bounds__(512) void kPW(
    const float* __restrict__ emb, const float* __restrict__ w_ih,
    const float* __restrict__ b_ih, float* __restrict__ P,
    const float* __restrict__ g_w2, const float* __restrict__ g_w3,
    const float* __restrict__ g_w4, ushort* __restrict__ Wst)
{
    int tid = threadIdx.x;
    if (blockIdx.x < 96) {
        __shared__ __align__(16) float te[300];
        int v = blockIdx.x;
        for (int k = tid; k < 300; k += 512) te[k] = tanhf(emb[v * 300 + k]);
        __syncthreads();
        int g = tid;
        float acc = b_ih[g];
        const float4* wr = (const float4*)(w_ih + g * 300);
        const float4* tv = (const float4*)te;
        for (int k = 0; k < 75; ++k) {
            float4 w4 = wr[k], t4 = tv[k];
            acc += w4.x * t4.x + w4.y * t4.y + w4.z * t4.z + w4.w * t4.w;
        }
        P[v * 512 + g] = acc;
    } else if (tid < 256) {
        int blk = blockIdx.x - 96;
        int li = blk >> 3, kc = blk & 7, col = tid;
        const float* W = (li == 0) ? g_w2 : (li == 1) ? g_w3 : g_w4;
        ushort* dst = Wst + li * 65536 + kc * 8192
                    + (col >> 4) * 512 + (col & 15) * 8;
        for (int kk = 0; kk < 32; ++kk)
            dst[(kk >> 3) * 128 + (kk & 7)] = f2bf(W[(kc * 32 + kk) * 256 + col]);
    }
}

// ---------------- kernel 2: fused LSTM -> Wq -> A1/A2, 512 threads, 1 gate/thread
#define WROW 132   // padded w_hh row (ushort): 264 B -> 2-way banks on b64 reads
__global__ __launch_bounds__(512) void kLA(
    const float* __restrict__ P, const float* __restrict__ w_hh,
    const float* __restrict__ b_hh, const float* __restrict__ g_w1,
    const float* __restrict__ g_b1, const int* __restrict__ q_feats,
    const int* __restrict__ q_lens, const float* __restrict__ box_feats,
    ushort* __restrict__ A1, ushort* __restrict__ A2)
{
    __shared__ __align__(16) ushort whh[512 * WROW];   // 135168 B
    __shared__ __align__(16) float h[128];
    __shared__ __align__(16) float c[128];
    __shared__ float gates[512];
    __shared__ float wq2[2][256];
    __shared__ float box[64][26];
    int b = blockIdx.x, tid = threadIdx.x;          // block 512
    if (tid < 128) { h[tid] = 0.f; c[tid] = 0.f; }
    for (int i = tid * 4; i < 65536; i += 2048) {
        int g = i >> 7, k = i & 127;
        float4 w4 = *(const float4*)&w_hh[i];
        uint2 o;
        o.x = cvtpk(w4.x, w4.y);
        o.y = cvtpk(w4.z, w4.w);
        *(uint2*)&whh[g * WROW + k] = o;
    }
    for (int idx = tid; idx < 64 * 26; idx += 512) {
        int n = idx / 26, d = idx - n * 26;
        float v;
        if (d < 24)       v = box_feats[(b * 64 + n) * 24 + d];
        else if (d == 24) v = ((n >> 3) - 4) * 0.125f;
        else              v = ((n & 7) - 4) * 0.125f;
        box[n][d] = v;
    }
    __syncthreads();
    int len = q_lens[b];
    const int g = tid;
    const ushort* wr = &whh[g * WROW];
    for (int t = 0; t < len; ++t) {
        int idx = q_feats[b * 20 + t];
        float acc = P[idx * 512 + g] + b_hh[g];
        #pragma unroll
        for (int k8 = 0; k8 < 16; ++k8) {
            uint2 wlo = *(const uint2*)&wr[k8 * 8];
            uint2 whi = *(const uint2*)&wr[k8 * 8 + 4];
            float4 h0 = *(const float4*)&h[k8 * 8];
            float4 h1 = *(const float4*)&h[k8 * 8 + 4];
            acc += bf2f((ushort)(wlo.x & 0xFFFFu)) * h0.x
                 + bf2f((ushort)(wlo.x >> 16))     * h0.y
                 + bf2f((ushort)(wlo.y & 0xFFFFu)) * h0.z
                 + bf2f((ushort)(wlo.y >> 16))     * h0.w
                 + bf2f((ushort)(whi.x & 0xFFFFu)) * h1.x
                 + bf2f((ushort)(whi.x >> 16))     * h1.y
                 + bf2f((ushort)(whi.y & 0xFFFFu)) * h1.z
                 + bf2f((ushort)(whi.y >> 16))     * h1.w;
        }
        gates[g] = acc;
        __syncthreads();
        if (tid < 128) {
            float ig = sigm(gates[tid]);
            float fg = sigm(gates[128 + tid]);
            float gg = tanhf(gates[256 + tid]);
            float og = sigm(gates[384 + tid]);
            float cn = fg * c[tid] + ig * gg;
            c[tid] = cn;
            h[tid] = og * tanhf(cn);
        }
        __syncthreads();
    }
    {
        int l = tid & 255, half = tid >> 8;
        float acc = (half == 0) ? g_b1[l] : 0.f;
        for (int k = 0; k < 64; ++k)
            acc += c[half * 64 + k] * g_w1[(52 + half * 64 + k) * 256 + l];
        wq2[half][l] = acc;
    }
    __syncthreads();
    {
        int l = tid & 255, n0 = tid >> 8;
        float w1a[26], w1b[26];
        #pragma unroll
        for (int d = 0; d < 26; ++d) {
            w1a[d] = g_w1[d * 256 + l];
            w1b[d] = g_w1[(26 + d) * 256 + l];
        }
        float wqv = wq2[0][l] + wq2[1][l];
        for (int n = n0; n < 64; n += 2) {
            float a1 = 0.f, a2 = wqv;
            #pragma unroll
            for (int d = 0; d < 26; ++d) {
                a1 += box[n][d] * w1a[d];
                a2 += box[n][d] * w1b[d];
            }
            A1[(b * 64 + n) * 256 + l] = f2bf(a1);
            A2[(b * 64 + n) * 256 + l] = f2bf(a2);
        }
    }
}

// ---------------- kernel 3: pair-MLP; W from L2, barrier-free K-loop,
//                  2 pairs/block (64KB LDS) -> 2 blocks/CU, 4 waves/SIMD
#define MFMA1(wa, xb, a) __builtin_amdgcn_mfma_f32_16x16x32_bf16(wa, xb, a, 0, 0, 0)

__global__ __launch_bounds__(512, 4) void kD(
    const ushort* __restrict__ A1, const ushort* __restrict__ A2,
    const ushort* __restrict__ Wst,
    const float* __restrict__ b2, const float* __restrict__ b3,
    const float* __restrict__ b4, float* __restrict__ partial)
{
    __shared__ __align__(16) ushort lds_x[128 * 256];   // 65536 B, XOR-swizzled rows

    const int tid = threadIdx.x;
    const int b = blockIdx.x >> 5, iblk = blockIdx.x & 31;   // 2 pairs: i = iblk*2+p
    const int lane = tid & 63, wv = tid >> 6;                // 8 waves
    const int l15 = lane & 15, lg = lane >> 4;
    const int col0 = wv * 32;            // wave tile: 128 rows x 32 EXCLUSIVE cols

    // ---- a1 rows in registers (transient)
    const int l0 = (tid & 31) << 3;
    bf16x8 a1r[2];
    #pragma unroll
    for (int p = 0; p < 2; ++p)
        a1r[p] = *(const bf16x8*)&A1[(b * 64 + iblk * 2 + p) * 256 + l0];

    // ---- build X1 (swizzled): X[p*64+j][l] = relu(a1[p][l] + A2[b,j][l])
    const ushort* A2b = A2 + b * 64 * 256;
    #pragma unroll
    for (int it = 0; it < 8; ++it) {
        int row = it * 16 + (tid >> 5);        // 0..127 each exactly once
        int j = row & 63;
        uint4 v = *(const uint4*)(A2b + j * 256 + l0);
        bf16x8 a1v = a1r[it >> 2];             // row>>6 == it>>2 (compile-time)
        uint vv[4] = {v.x, v.y, v.z, v.w}, ov[4];
        #pragma unroll
        for (int qq = 0; qq < 4; ++qq) {
            float f0 = bf2f((ushort)a1v[2 * qq])     + bf2f((ushort)(vv[qq] & 0xFFFFu));
            float f1 = bf2f((ushort)a1v[2 * qq + 1]) + bf2f((ushort)(vv[qq] >> 16));
            ov[qq] = cvtpk(fmaxf(f0, 0.f), fmaxf(f1, 0.f));
        }
        *(uint4*)&lds_x[row * 256 + (l0 ^ ((row & 7) << 3))] =
            make_uint4(ov[0], ov[1], ov[2], ov[3]);
    }
    __syncthreads();   // X ready

    // per-lane W base: this wave's 2 col-groups start at (col0>>4)*1KB; lane*16B
    const char* wbase = (const char*)Wst + (col0 >> 4) * 1024 + lane * 16;

    #pragma unroll 1
    for (int li = 0; li < 3; ++li) {
        f32x4 acc[8][2];
        #pragma unroll
        for (int rt = 0; rt < 8; ++rt) {
            acc[rt][0] = (f32x4){0.f, 0.f, 0.f, 0.f};
            acc[rt][1] = (f32x4){0.f, 0.f, 0.f, 0.f};
        }

        // ---- barrier-free K-loop: W straight from L2, X from LDS (read-only)
        #pragma unroll 1
        for (int kc = 0; kc < 8; ++kc) {
            const char* wp = wbase + li * 131072 + kc * 16384;
            bf16x8 wa0 = *(const bf16x8*)(wp);
            bf16x8 wa1 = *(const bf16x8*)(wp + 1024);
            bf16x8 xb[8];
            #pragma unroll
            for (int rt = 0; rt < 8; ++rt) {
                int row = rt * 16 + l15;
                xb[rt] = *(const bf16x8*)
                    &lds_x[row * 256 + ((kc * 32 + lg * 8) ^ ((row & 7) << 3))];
            }
            __builtin_amdgcn_s_setprio(1);
            #pragma unroll
            for (int rt = 0; rt < 8; ++rt) {
                acc[rt][0] = MFMA1(wa0, xb[rt], acc[rt][0]);
                acc[rt][1] = MFMA1(wa1, xb[rt], acc[rt][1]);
            }
            __builtin_amdgcn_s_setprio(0);
        }

        const float* bias = (li == 0) ? b2 : (li == 1) ? b3 : b4;
        f32x4 bv0 = *(const f32x4*)(bias + col0 + lg * 4);
        f32x4 bv1 = *(const f32x4*)(bias + col0 + 16 + lg * 4);

        if (li < 2) {
            __builtin_amdgcn_s_barrier();   // all waves done reading lds_x this layer
            #pragma unroll
            for (int rt = 0; rt < 8; ++rt) {
                int row = rt * 16 + l15;
                int sw = (row & 7) << 3;
                f32x4 a0 = acc[rt][0], a1 = acc[rt][1];
                uint2 pk0, pk1;
                pk0.x = cvtpk(fmaxf(a0[0] + bv0[0], 0.f), fmaxf(a0[1] + bv0[1], 0.f));
                pk0.y = cvtpk(fmaxf(a0[2] + bv0[2], 0.f), fmaxf(a0[3] + bv0[3], 0.f));
                pk1.x = cvtpk(fmaxf(a1[0] + bv1[0], 0.f), fmaxf(a1[1] + bv1[1], 0.f));
                pk1.y = cvtpk(fmaxf(a1[2] + bv1[2], 0.f), fmaxf(a1[3] + bv1[3], 0.f));
                *(uint2*)&lds_x[row * 256 + ((col0 + lg * 4) ^ sw)] = pk0;
                *(uint2*)&lds_x[row * 256 + ((col0 + 16 + lg * 4) ^ sw)] = pk1;
            }
            asm volatile("s_waitcnt lgkmcnt(0)" ::: "memory");
            __builtin_amdgcn_sched_barrier(0);
            __builtin_amdgcn_s_barrier();   // new X visible to all
        } else {
            // ---- final layer: pair p=0 from rt 0-3, p=1 from rt 4-7
            #pragma unroll
            for (int p = 0; p < 2; ++p) {
                f32x4 s0 = {0.f, 0.f, 0.f, 0.f}, s1 = {0.f, 0.f, 0.f, 0.f};
                #pragma unroll
                for (int r = 0; r < 4; ++r) {
                    f32x4 a0 = acc[p * 4 + r][0], a1 = acc[p * 4 + r][1];
                    s0[0] += fmaxf(a0[0] + bv0[0], 0.f);
                    s0[1] += fmaxf(a0[1] + bv0[1], 0.f);
                    s0[2] += fmaxf(a0[2] + bv0[2], 0.f);
                    s0[3] += fmaxf(a0[3] + bv0[3], 0.f);
                    s1[0] += fmaxf(a1[0] + bv1[0], 0.f);
                    s1[1] += fmaxf(a1[1] + bv1[1], 0.f);
                    s1[2] += fmaxf(a1[2] + bv1[2], 0.f);
                    s1[3] += fmaxf(a1[3] + bv1[3], 0.f);
                }
                #pragma unroll
                for (int m = 1; m < 16; m <<= 1) {
                    #pragma unroll
                    for (int r = 0; r < 4; ++r) {
                        s0[r] += __shfl_xor(s0[r], m, 64);
                        s1[r] += __shfl_xor(s1[r], m, 64);
                    }
                }
                if (l15 == 0) {
                    int prow = b * 64 + iblk * 2 + p;
                    float4 o0 = {s0[0], s0[1], s0[2], s0[3]};
                    float4 o1 = {s1[0], s1[1], s1[2], s1[3]};
                    *(float4*)&partial[prow * 256 + col0 + lg * 4] = o0;
                    *(float4*)&partial[prow * 256 + col0 + 16 + lg * 4] = o1;
                }
            }
        }
    }
}

// ---------------- kernel 4: fused reduce + f-network, one block per b
__global__ __launch_bounds__(256) void kRF(
    const float* __restrict__ partial,
    const float* __restrict__ f_w1, const float* __restrict__ f_b1,
    const float* __restrict__ f_w2, const float* __restrict__ f_b2,
    const float* __restrict__ f_w3, const float* __restrict__ f_b3,
    float* __restrict__ out)
{
    __shared__ float g[256], y1[256], y2[256];
    int b = blockIdx.x, t = threadIdx.x;       // block 256
    {
        float s = 0.f;
        const float* pb = partial + b * 64 * 256 + t;
        #pragma unroll 8
        for (int i = 0; i < 64; ++i) s += pb[i * 256];
        g[t] = s;
    }
    __syncthreads();
    float acc = f_b1[t];
    for (int k = 0; k < 256; ++k) acc += g[k] * f_w1[k * 256 + t];
    y1[t] = fmaxf(acc, 0.f);
    __syncthreads();
    acc = f_b2[t];
    for (int k = 0; k < 256; ++k) acc += y1[k] * f_w2[k * 256 + t];
    y2[t] = fmaxf(acc, 0.f);
    __syncthreads();
    if (t < 100) {
        float o = f_b3[t];
        for (int k = 0; k < 256; ++k) o += y2[k] * f_w3[k * 100 + t];
        out[b * 100 + t] = o;
    }
}

extern "C" void kernel_launch(void* const* d_in, const int* in_sizes, int n_in,
                              void* d_out, int out_size, void* d_ws, size_t ws_size,
                              hipStream_t stream)
{
    const float* box_feats = (const float*)d_in[0];
    const float* emb   = (const float*)d_in[1];
    const float* w_ih  = (const float*)d_in[2];
    const float* w_hh  = (const float*)d_in[3];
    const float* b_ih  = (const float*)d_in[4];
    const float* b_hh  = (const float*)d_in[5];
    const float* g_w1  = (const float*)d_in[6];
    const float* g_b1  = (const float*)d_in[7];
    const float* g_w2  = (const float*)d_in[8];
    const float* g_b2  = (const float*)d_in[9];
    const float* g_w3  = (const float*)d_in[10];
    const float* g_b3  = (const float*)d_in[11];
    const float* g_w4  = (const float*)d_in[12];
    const float* g_b4  = (const float*)d_in[13];
    const float* f_w1  = (const float*)d_in[14];
    const float* f_b1  = (const float*)d_in[15];
    const float* f_w2  = (const float*)d_in[16];
    const float* f_b2  = (const float*)d_in[17];
    const float* f_w3  = (const float*)d_in[18];
    const float* f_b3  = (const float*)d_in[19];
    const int* q_feats = (const int*)d_in[20];
    const int* q_lens  = (const int*)d_in[21];
    float* out = (float*)d_out;

    char* ws = (char*)d_ws;
    float*  P    = (float*) (ws + 0);          //  96*512*4   = 196608
    ushort* A1   = (ushort*)(ws + 196608);     // 8192*256*2  = 4194304
    ushort* A2   = (ushort*)(ws + 4390912);    // 8192*256*2  = 4194304
    ushort* Wst  = (ushort*)(ws + 8585216);    // 3*65536*2   = 393216
    float*  part = (float*) (ws + 8978432);    // 8192*256*4  = 8388608

    hipLaunchKernelGGL(kPW, dim3(120),  dim3(512), 0, stream,
                       emb, w_ih, b_ih, P, g_w2, g_w3, g_w4, Wst);
    hipLaunchKernelGGL(kLA, dim3(128),  dim3(512), 0, stream,
                       P, w_hh, b_hh, g_w1, g_b1, q_feats, q_lens, box_feats, A1, A2);
    hipLaunchKernelGGL(kD,  dim3(4096), dim3(512), 0, stream,
                       A1, A2, Wst, g_b2, g_b3, g_b4, part);
    hipLaunchKernelGGL(kRF, dim3(128),  dim3(256), 0, stream,
                       part, f_w1, f_b1, f_w2, f_b2, f_w3, f_b3, out);
}